// Round 1
// baseline (1549.130 us; speedup 1.0000x reference)
//
#include <hip/hip_runtime.h>
#include <math.h>

#define F_DIM 128
#define CHUNK 2048   // logits/e buffer capacity per chunk (8 KB LDS)

// One block per graph. batch_idx is sorted -> segment [start,end) found by
// binary search. Online softmax over chunks so arbitrarily large segments work.
// Phase A: wave-per-row logits (lane = float2 of the row, shuffle reduce).
// Phase C: 128 f-lanes x 2 row-streams weighted accumulation; re-reads x rows
// that were just streamed in phase A (small reuse distance -> L2/L3 hit).
__global__ __launch_bounds__(256)
void node_attn_pool_kernel(const float* __restrict__ x,
                           const float* __restrict__ attn_w,
                           const int*   __restrict__ bidx,
                           float* __restrict__ out,
                           int n_total) {
    const int g    = blockIdx.x;
    const int tid  = threadIdx.x;
    const int lane = tid & 63;
    const int wave = tid >> 6;        // 0..3

    // ---- segment bounds: start = lower_bound(g), end = lower_bound(g+1) ----
    // All threads redundantly: identical path -> broadcast loads, cheap.
    int lo = 0, hi = n_total;
    while (lo < hi) { int mid = (lo + hi) >> 1; if (bidx[mid] < g)     lo = mid + 1; else hi = mid; }
    const int start = lo;
    hi = n_total;
    while (lo < hi) { int mid = (lo + hi) >> 1; if (bidx[mid] < g + 1) lo = mid + 1; else hi = mid; }
    const int end = lo;

    __shared__ float lds_e[CHUNK];
    __shared__ float red[4];
    __shared__ float s_bcast;
    __shared__ float accbuf[F_DIM];

    // per-lane slice of w for the logit dot product (dims 2*lane, 2*lane+1)
    const float2 w2 = ((const float2*)attn_w)[lane];

    const int r = tid >> 7;           // 0/1: which row-stream in phase C
    const int f = tid & 127;          // feature dim owned in phase C

    float m_run = -INFINITY;          // running max
    float l_run = 0.f;                // running sum of exp
    float acc   = 0.f;                // partial pooled[f] for row-stream r

    for (int s = start; s < end; s += CHUNK) {
        const int c = min(CHUNK, end - s);

        // ---- Phase A: logits for rows [s, s+c) ----
        for (int j = wave; j < c; j += 4) {
            const float2 xv = ((const float2*)(x + (size_t)(s + j) * F_DIM))[lane];
            float d = xv.x * w2.x + xv.y * w2.y;
            #pragma unroll
            for (int off = 32; off > 0; off >>= 1) d += __shfl_down(d, off);
            if (lane == 0) lds_e[j] = d;
        }
        __syncthreads();

        // ---- chunk max (block reduce) ----
        float cm = -INFINITY;
        for (int j = tid; j < c; j += 256) cm = fmaxf(cm, lds_e[j]);
        #pragma unroll
        for (int off = 32; off > 0; off >>= 1) cm = fmaxf(cm, __shfl_down(cm, off));
        if (lane == 0) red[wave] = cm;
        __syncthreads();
        if (tid == 0) s_bcast = fmaxf(fmaxf(red[0], red[1]), fmaxf(red[2], red[3]));
        __syncthreads();

        const float m_new = fmaxf(m_run, s_bcast);
        const float scale = __expf(m_run - m_new);   // first chunk: exp(-inf)=0
        l_run *= scale;
        acc   *= scale;
        m_run  = m_new;

        // ---- e_j = exp(logit - m), chunk sum ----
        float csum = 0.f;
        for (int j = tid; j < c; j += 256) {
            const float e = __expf(lds_e[j] - m_new);
            lds_e[j] = e;               // slot j touched only by this thread
            csum += e;
        }
        #pragma unroll
        for (int off = 32; off > 0; off >>= 1) csum += __shfl_down(csum, off);
        if (lane == 0) red[wave] = csum;
        __syncthreads();                 // e-writes + red visible
        l_run += red[0] + red[1] + red[2] + red[3];

        // ---- Phase C: acc[f] += e_j * x[s+j][f] ----
        for (int j = r; j < c; j += 2) {
            acc += lds_e[j] * x[(size_t)(s + j) * F_DIM + f];
        }
        __syncthreads();                 // before next chunk overwrites lds_e
    }

    // ---- combine the two row-stream partials, normalize, store ----
    if (r == 1) accbuf[f] = acc;
    __syncthreads();
    if (r == 0) {
        const float tot = acc + accbuf[f];
        out[(size_t)g * F_DIM + f] = tot / (l_run + 1e-16f);
    }
}

extern "C" void kernel_launch(void* const* d_in, const int* in_sizes, int n_in,
                              void* d_out, int out_size, void* d_ws, size_t ws_size,
                              hipStream_t stream) {
    const float* x      = (const float*)d_in[0];
    const float* attn_w = (const float*)d_in[1];
    // d_in[2] = attn_b: cancels inside the segment softmax -> unused.
    const int*   bidx   = (const int*)d_in[3];

    const int n_total    = in_sizes[0] / F_DIM;
    const int num_graphs = out_size / F_DIM;

    node_attn_pool_kernel<<<num_graphs, 256, 0, stream>>>(
        x, attn_w, bidx, (float*)d_out, n_total);
}

// Round 2
// 1286.056 us; speedup vs baseline: 1.2046x; 1.2046x over previous
//
#include <hip/hip_runtime.h>
#include <math.h>

#define F_DIM 128
#define CHUNK 64            // rows per chunk; 8 float4 per thread held in VGPRs

// ---------------------------------------------------------------------------
// Kernel 1: segment boundaries from sorted batch_idx.
// seg[g] = first row with bidx >= g ; seg[G] = n. Covers empty graphs.
// d_ws is re-poisoned (0xAA) before every call -> must write ALL G+1 entries.
// ---------------------------------------------------------------------------
__global__ void seg_bounds_kernel(const int* __restrict__ bidx,
                                  int* __restrict__ seg, int n, int G) {
    int i = blockIdx.x * blockDim.x + threadIdx.x;
    if (i >= n) return;
    int cur = bidx[i];
    if (i == 0) {
        for (int g = 0; g <= cur; ++g) seg[g] = 0;
    } else {
        int prev = bidx[i - 1];
        for (int g = prev + 1; g <= cur; ++g) seg[g] = i;
    }
    if (i == n - 1) {
        for (int g = cur + 1; g <= G; ++g) seg[g] = n;
    }
}

// ---------------------------------------------------------------------------
// Kernel 2: one block (256 thr) per graph. Online softmax over 64-row chunks.
// Thread t owns feature slice 4*(t&31); group grp = t>>5 owns rows i*8+grp.
// x is read once from HBM; the chunk lives in registers (x4[8]).
// ---------------------------------------------------------------------------
__global__ __launch_bounds__(256)
void node_attn_pool_kernel(const float* __restrict__ x,
                           const float* __restrict__ attn_w,
                           const int*   __restrict__ seg,
                           float* __restrict__ out) {
    const int g    = blockIdx.x;
    const int tid  = threadIdx.x;
    const int lane = tid & 63;
    const int wave = tid >> 6;
    const int grp  = tid >> 5;          // 0..7: row group
    const int fq   = tid & 31;          // feature quad: features 4*fq..4*fq+3

    const int start = seg[g];
    const int end   = seg[g + 1];

    __shared__ float lds_logit[CHUNK];
    __shared__ float lds_e[CHUNK];
    __shared__ float s_m, s_l;
    __shared__ float lds_red[4 * F_DIM];

    const float4 w4 = ((const float4*)attn_w)[fq];

    float m_run = -INFINITY;
    float l_run = 0.f;
    float4 acc  = make_float4(0.f, 0.f, 0.f, 0.f);
    float4 x4[8];

    const float4* xp = (const float4*)x;

    for (int s = start; s < end; s += CHUNK) {
        const int c = min(CHUNK, end - s);
        const size_t cbase = (size_t)s * (F_DIM / 4);   // float4 index of chunk

        // ---- staging + fused logit partials ----
        #pragma unroll
        for (int i = 0; i < 8; ++i) {
            const int ri = i * 8 + grp;                 // row within chunk
            float4 v = make_float4(0.f, 0.f, 0.f, 0.f);
            if (ri < c) v = xp[cbase + (size_t)i * 256 + tid];
            x4[i] = v;
            float d = v.x * w4.x + v.y * w4.y + v.z * w4.z + v.w * w4.w;
            d += __shfl_down(d, 16, 32);
            d += __shfl_down(d,  8, 32);
            d += __shfl_down(d,  4, 32);
            d += __shfl_down(d,  2, 32);
            d += __shfl_down(d,  1, 32);
            if (fq == 0 && ri < c) lds_logit[ri] = d;
        }
        __syncthreads();

        // ---- chunk max (wave 0) ----
        if (wave == 0) {
            float v = (lane < c) ? lds_logit[lane] : -INFINITY;
            v = fmaxf(v, __shfl_down(v, 32));
            v = fmaxf(v, __shfl_down(v, 16));
            v = fmaxf(v, __shfl_down(v,  8));
            v = fmaxf(v, __shfl_down(v,  4));
            v = fmaxf(v, __shfl_down(v,  2));
            v = fmaxf(v, __shfl_down(v,  1));
            if (lane == 0) s_m = v;
        }
        __syncthreads();

        const float m_new = fmaxf(m_run, s_m);
        const float scale = __expf(m_run - m_new);      // first chunk: exp(-inf)=0
        m_run  = m_new;
        l_run *= scale;
        acc.x *= scale; acc.y *= scale; acc.z *= scale; acc.w *= scale;

        // ---- e_j + chunk sum (wave 0) ----
        if (wave == 0) {
            float e = (lane < c) ? __expf(lds_logit[lane] - m_new) : 0.f;
            if (lane < c) lds_e[lane] = e;
            e += __shfl_down(e, 32);
            e += __shfl_down(e, 16);
            e += __shfl_down(e,  8);
            e += __shfl_down(e,  4);
            e += __shfl_down(e,  2);
            e += __shfl_down(e,  1);
            if (lane == 0) s_l = e;
        }
        __syncthreads();

        l_run += s_l;

        // ---- weighted accumulate from registers ----
        #pragma unroll
        for (int i = 0; i < 8; ++i) {
            const int ri = i * 8 + grp;
            if (ri < c) {
                const float e = lds_e[ri];
                acc.x += e * x4[i].x;
                acc.y += e * x4[i].y;
                acc.z += e * x4[i].z;
                acc.w += e * x4[i].w;
            }
        }
        __syncthreads();    // lds_e / lds_logit reused next chunk
    }

    // ---- reduce the 8 row-groups: pairs within wave, then 4 waves via LDS ----
    acc.x += __shfl_down(acc.x, 32);
    acc.y += __shfl_down(acc.y, 32);
    acc.z += __shfl_down(acc.z, 32);
    acc.w += __shfl_down(acc.w, 32);
    if (lane < 32) ((float4*)(lds_red + wave * F_DIM))[lane] = acc;
    __syncthreads();

    if (tid < F_DIM) {
        const float tot = lds_red[tid] + lds_red[F_DIM + tid] +
                          lds_red[2 * F_DIM + tid] + lds_red[3 * F_DIM + tid];
        out[(size_t)g * F_DIM + tid] = tot / (l_run + 1e-16f);
    }
}

extern "C" void kernel_launch(void* const* d_in, const int* in_sizes, int n_in,
                              void* d_out, int out_size, void* d_ws, size_t ws_size,
                              hipStream_t stream) {
    const float* x      = (const float*)d_in[0];
    const float* attn_w = (const float*)d_in[1];
    // d_in[2] = attn_b: cancels inside the segment softmax -> unused.
    const int*   bidx   = (const int*)d_in[3];

    const int n_total    = in_sizes[0] / F_DIM;
    const int num_graphs = out_size / F_DIM;

    int* seg = (int*)d_ws;   // G+1 ints

    seg_bounds_kernel<<<(n_total + 255) / 256, 256, 0, stream>>>(
        bidx, seg, n_total, num_graphs);

    node_attn_pool_kernel<<<num_graphs, 256, 0, stream>>>(
        x, attn_w, seg, (float*)d_out);
}